// Round 9
// baseline (1101.756 us; speedup 1.0000x reference)
//
#include <hip/hip_runtime.h>

#define B_ 8
#define N_ 8192
#define DIN_ 16
#define G_ 512
#define K_ 32
#define OD_ 256
#define PD_ 128
#define MD_ 128
#define CE_ 259
#define EST 168    // E row stride (bf16 elems)
#define XST2 264   // x tile row stride
#define HST 136    // h tile row stride
#define AL1K 160   // lin1 K padded 131->160

typedef __attribute__((ext_vector_type(8))) short short8t;
typedef __attribute__((ext_vector_type(4))) float f32x4;
#define MFMA16(a, b, c) __builtin_amdgcn_mfma_f32_16x16x32_bf16((a), (b), (c), 0, 0, 0)

__device__ __forceinline__ ushort bf16_rne(float x) {
    unsigned u = __float_as_uint(x);
    return (ushort)((u + 0x7FFFu + ((u >> 16) & 1u)) >> 16);
}
__device__ __forceinline__ void bf16_split(float x, ushort& h, ushort& l) {
    h = bf16_rne(x);
    float hf = __uint_as_float((unsigned)h << 16);
    l = bf16_rne(x - hf);
}

// ---- DPP wave64 reductions (VALU-only)
#define DPP_STEP_MAXF(x, ctrl) { int _t = __builtin_amdgcn_update_dpp(            \
        __float_as_int(x), __float_as_int(x), (ctrl), 0xF, 0xF, false);           \
        (x) = fmaxf((x), __int_as_float(_t)); }
#define DPP_STEP_MINF(x, ctrl) { int _t = __builtin_amdgcn_update_dpp(            \
        __float_as_int(x), __float_as_int(x), (ctrl), 0xF, 0xF, false);           \
        (x) = fminf((x), __int_as_float(_t)); }
#define DPP_STEP_MINU(x, ctrl) { int _t = __builtin_amdgcn_update_dpp(            \
        (int)(x), (int)(x), (ctrl), 0xF, 0xF, false);                             \
        unsigned _u = (unsigned)_t; (x) = ((x) < _u) ? (x) : _u; }

__device__ __forceinline__ float wave_max_f32(float x) {
    DPP_STEP_MAXF(x, 0x121); DPP_STEP_MAXF(x, 0x122);
    DPP_STEP_MAXF(x, 0x124); DPP_STEP_MAXF(x, 0x128);
    DPP_STEP_MAXF(x, 0x142); DPP_STEP_MAXF(x, 0x143);
    return __int_as_float(__builtin_amdgcn_readlane(__float_as_int(x), 63));
}
__device__ __forceinline__ float wave_min_f32(float x) {
    DPP_STEP_MINF(x, 0x121); DPP_STEP_MINF(x, 0x122);
    DPP_STEP_MINF(x, 0x124); DPP_STEP_MINF(x, 0x128);
    DPP_STEP_MINF(x, 0x142); DPP_STEP_MINF(x, 0x143);
    return __int_as_float(__builtin_amdgcn_readlane(__float_as_int(x), 63));
}
__device__ __forceinline__ unsigned wave_min_u32(unsigned x) {
    DPP_STEP_MINU(x, 0x121); DPP_STEP_MINU(x, 0x122);
    DPP_STEP_MINU(x, 0x124); DPP_STEP_MINU(x, 0x128);
    DPP_STEP_MINU(x, 0x142); DPP_STEP_MINU(x, 0x143);
    return (unsigned)__builtin_amdgcn_readlane((int)x, 63);
}

// ---------------- prep: fragment-ordered bf16 hi/lo weight planes ----------------
__global__ __launch_bounds__(256)
void prep_kernel(const float* __restrict__ w_lin1, const float* __restrict__ down_w,
                 const float* __restrict__ up_w, const float* __restrict__ w_embed,
                 float* __restrict__ wta, float* __restrict__ wEtg,
                 ushort* __restrict__ alf, ushort* __restrict__ adf,
                 ushort* __restrict__ auf) {
    int i = blockIdx.x * blockDim.x + threadIdx.x;
    if (i < PD_ * OD_) {                        // wta[j][c] = w_lin1[c][131+j]
        int j = i >> 8, c = i & 255;
        wta[i] = w_lin1[c * CE_ + 131 + j];
    }
    if (i < DIN_ * PD_) {                       // wEtg[r][c] = w_embed[c][r]
        int r = i >> 7, c = i & 127;
        wEtg[i] = w_embed[c * DIN_ + r];
    }
    if (i < 5120) {                             // alf: mtile in [0,16), kbi in [0,5)
        int lane = i & 63, t = i >> 6;
        int kbi = t % 5, mtile = t / 5;
        int m = mtile * 16 + (lane & 15), g16 = lane >> 4;
        int dst = i * 8;
#pragma unroll
        for (int j = 0; j < 8; ++j) {
            int k = kbi * 32 + g16 * 8 + j;
            float v = (k < 131) ? w_lin1[m * CE_ + k] : 0.f;
            ushort h, l; bf16_split(v, h, l);
            alf[dst + j] = h; alf[dst + j + 40960] = l;
        }
    }
    if (i < 8192) {                             // adf: t = ((l*8+mtile)*8+kbi)
        int lane = i & 63, t = i >> 6;
        int kbi = t & 7, mtile = (t >> 3) & 7, l = t >> 6;
        int m = mtile * 16 + (lane & 15), g16 = lane >> 4;
        int dst = i * 8;
#pragma unroll
        for (int j = 0; j < 8; ++j) {
            int k = kbi * 32 + g16 * 8 + j;
            float v = down_w[(l * MD_ + m) * OD_ + k];
            ushort h, lo; bf16_split(v, h, lo);
            adf[dst + j] = h; adf[dst + j + 65536] = lo;
        }
    }
    if (i < 8192) {                             // auf: t = ((l*16+mtile)*4+kbi)
        int lane = i & 63, t = i >> 6;
        int kbi = t & 3, mtile = (t >> 2) & 15, l = t >> 6;
        int m = mtile * 16 + (lane & 15), g16 = lane >> 4;
        int dst = i * 8;
#pragma unroll
        for (int j = 0; j < 8; ++j) {
            int k = kbi * 32 + g16 * 8 + j;
            float v = up_w[(l * OD_ + m) * MD_ + k];
            ushort h, lo; bf16_split(v, h, lo);
            auf[dst + j] = h; auf[dst + j + 65536] = lo;
        }
    }
}

// ---------------- FPS: 512 thr / 8 waves; NO global stores in the barrier loop ----------------
// Selections buffered in LDS (sel_s) and dumped once — avoids the per-iteration
// vmcnt(0)-drain the compiler inserts before s_barrier after a global store.
__global__ __launch_bounds__(512)
void fps_kernel(const float* __restrict__ xyz, int* __restrict__ sel) {
#pragma clang fp contract(off)
    __shared__ unsigned long long wred[2][8];
    __shared__ float4 wpt[2][8];
    __shared__ int sel_s[G_];
    int b = blockIdx.x, tid = threadIdx.x;
    const float* xb = xyz + (size_t)b * N_ * 3;
    float px[16], py[16], pz[16], mind[16];
    float bv = -1.f, bx = 0.f, by = 0.f, bz = 0.f; int bi = 0;
#pragma unroll
    for (int j = 0; j < 16; ++j) {
        int idx = tid + j * 512;
        px[j] = xb[idx * 3]; py[j] = xb[idx * 3 + 1]; pz[j] = xb[idx * 3 + 2];
        mind[j] = 1e10f;
        float ss = (px[j] * px[j] + py[j] * py[j]) + pz[j] * pz[j];
        if (ss > bv) { bv = ss; bi = idx; bx = px[j]; by = py[j]; bz = pz[j]; }
    }
    int wv = tid >> 6;
    {
        float wm = wave_max_f32(bv);
        unsigned mi = (bv == wm) ? (unsigned)bi : 0xFFFFFFFFu;
        unsigned wi = wave_min_u32(mi);
        if ((tid & 63) == 0)
            wred[0][wv] = ((unsigned long long)__float_as_uint(wm) << 32)
                        | (unsigned long long)(0xFFFFFFFFu - wi);
        if (bv == wm && (unsigned)bi == wi)
            wpt[0][wv] = make_float4(bx, by, bz, 0.f);
    }
    __syncthreads();
    unsigned long long best = wred[0][0]; int wb = 0;
#pragma unroll
    for (int i = 1; i < 8; ++i) { unsigned long long v = wred[0][i]; if (v > best) { best = v; wb = i; } }
    int cur = (int)(0xFFFFFFFFu - (unsigned)(best & 0xFFFFFFFFull));
    float4 cc = wpt[0][wb];
    float cx = cc.x, cy = cc.y, cz = cc.z;

    for (int it = 0; it < G_; ++it) {
        if (tid == 0) sel_s[it] = cur;
        bv = -1.f; bi = 0; bx = 0.f; by = 0.f; bz = 0.f;
#pragma unroll
        for (int j = 0; j < 16; ++j) {
            float dx = px[j] - cx, dy = py[j] - cy, dz = pz[j] - cz;
            float d = (dx * dx + dy * dy) + dz * dz;
            float m = fminf(mind[j], d); mind[j] = m;
            if (m > bv) { bv = m; bi = tid + j * 512; bx = px[j]; by = py[j]; bz = pz[j]; }
        }
        float wm = wave_max_f32(bv);
        unsigned mi = (bv == wm) ? (unsigned)bi : 0xFFFFFFFFu;
        unsigned wi = wave_min_u32(mi);
        int pb = (it + 1) & 1;
        if ((tid & 63) == 0)
            wred[pb][wv] = ((unsigned long long)__float_as_uint(wm) << 32)
                         | (unsigned long long)(0xFFFFFFFFu - wi);
        if (bv == wm && (unsigned)bi == wi)
            wpt[pb][wv] = make_float4(bx, by, bz, 0.f);
        __syncthreads();
        best = wred[pb][0]; wb = 0;
#pragma unroll
        for (int i = 1; i < 8; ++i) { unsigned long long v = wred[pb][i]; if (v > best) { best = v; wb = i; } }
        cur = (int)(0xFFFFFFFFu - (unsigned)(best & 0xFFFFFFFFull));
        cc = wpt[pb][wb];
        cx = cc.x; cy = cc.y; cz = cc.z;
    }
    __syncthreads();
    sel[b * G_ + tid] = sel_s[tid];
}

// ---------------- KNN: DPP argmin; picks buffered in LDS ----------------
__global__ __launch_bounds__(256)
void knn_kernel(const float* __restrict__ xyz, const int* __restrict__ sel,
                int* __restrict__ nn) {
#pragma clang fp contract(off)
    __shared__ float dld[N_];
    __shared__ unsigned long long wred[2][4];
    __shared__ int nn_s[K_];
    int gb = blockIdx.x; int b = gb >> 9, s = gb & (G_ - 1);
    const float* xb = xyz + (size_t)b * N_ * 3;
    int q = sel[b * G_ + s];
    float qx = xb[q * 3], qy = xb[q * 3 + 1], qz = xb[q * 3 + 2];
    float qq = (qx * qx + qy * qy) + qz * qz;
    int tid = threadIdx.x;
    const float FINF = __builtin_inff();
    float lv = FINF; int li = tid;
#pragma unroll 4
    for (int j = 0; j < 32; ++j) {
        int n = tid + j * 256;
        float rx = xb[n * 3], ry = xb[n * 3 + 1], rz = xb[n * 3 + 2];
        float rr = (rx * rx + ry * ry) + rz * rz;
        float dt = (qx * rx + qy * ry) + qz * rz;
        float d = (qq + rr) - 2.0f * dt;
        d = fmaxf(d, 0.f);
        dld[n] = d;
        if (d < lv) { lv = d; li = n; }
    }
    {
        float wm = wave_min_f32(lv);
        unsigned mi = (lv == wm) ? (unsigned)li : 0xFFFFFFFFu;
        unsigned wi = wave_min_u32(mi);
        if ((tid & 63) == 0)
            wred[0][tid >> 6] = ((unsigned long long)__float_as_uint(wm) << 32)
                              | (unsigned long long)wi;
    }
    __syncthreads();
    unsigned long long best = wred[0][0];
#pragma unroll
    for (int i = 1; i < 4; ++i) { unsigned long long v = wred[0][i]; if (v < best) best = v; }
    int win = (int)(best & 0xFFFFFFFFull);

    for (int t = 0; t < K_; ++t) {
        if (tid == 0) nn_s[t] = win;
        if ((win & 255) == tid) {
            dld[win] = FINF;
            lv = FINF; li = tid;
            for (int j = 0; j < 32; ++j) {
                float d = dld[tid + j * 256];
                if (d < lv) { lv = d; li = tid + j * 256; }
            }
        }
        float wm = wave_min_f32(lv);
        unsigned mi = (lv == wm) ? (unsigned)li : 0xFFFFFFFFu;
        unsigned wi = wave_min_u32(mi);
        int pb = (t + 1) & 1;
        if ((tid & 63) == 0)
            wred[pb][tid >> 6] = ((unsigned long long)__float_as_uint(wm) << 32)
                               | (unsigned long long)wi;
        __syncthreads();
        best = wred[pb][0];
#pragma unroll
        for (int i = 1; i < 4; ++i) { unsigned long long v = wred[pb][i]; if (v < best) best = v; }
        win = (int)(best & 0xFFFFFFFFull);
    }
    if (tid < K_) nn[(size_t)gb * K_ + tid] = nn_s[tid];
}

// ---------------- global std (ddof=1) ----------------
__global__ void std_acc_kernel(const float* __restrict__ xyz, const int* __restrict__ sel,
                               const int* __restrict__ nn, double* __restrict__ acc) {
    int tot = B_ * G_ * K_;
    int stride = gridDim.x * blockDim.x;
    double ls = 0.0, lss = 0.0;
    for (int idx = blockIdx.x * blockDim.x + threadIdx.x; idx < tot; idx += stride) {
        int b = idx >> 14; int g = (idx >> 5) & (G_ - 1);
        int n = nn[idx]; int a = sel[b * G_ + g];
        const float* xb = xyz + (size_t)b * N_ * 3;
#pragma unroll
        for (int c = 0; c < 3; ++c) {
            float v = xb[n * 3 + c] - xb[a * 3 + c];
            ls += (double)v; lss += (double)v * (double)v;
        }
    }
#pragma unroll
    for (int off = 32; off > 0; off >>= 1) {
        ls += __shfl_down(ls, off); lss += __shfl_down(lss, off);
    }
    if ((threadIdx.x & 63) == 0) { atomicAdd(acc, ls); atomicAdd(acc + 1, lss); }
}

__global__ void std_fin_kernel(const double* __restrict__ acc, float* __restrict__ stdp) {
    double s = acc[0], ss = acc[1];
    double M = (double)(B_ * G_ * K_ * 3);
    double var = (ss - s * s / M) / (M - 1.0);
    stdp[0] = (float)sqrt(var) + 1e-5f;
}

// ---------------- fused per-group pipeline, MFMA split-bf16 GEMMs ----------------
__global__ __launch_bounds__(256, 3)
void group_kernel(const float* __restrict__ xyz, const float* __restrict__ feat,
                  const float* __restrict__ wEtg, const float* __restrict__ bE,
                  const float* __restrict__ gE, const float* __restrict__ beE,
                  const int* __restrict__ sel, const int* __restrict__ nn,
                  const float* __restrict__ wta,
                  const ushort* __restrict__ alf, const ushort* __restrict__ adf,
                  const ushort* __restrict__ auf,
                  const float* __restrict__ g_lin1, const float* __restrict__ be_lin1,
                  const float* __restrict__ down_b, const float* __restrict__ gd,
                  const float* __restrict__ bd,
                  const float* __restrict__ up_b, const float* __restrict__ gu,
                  const float* __restrict__ bu,
                  const float* __restrict__ stdp, float* __restrict__ out) {
    __shared__ __align__(16) ushort smem[25600];
    __shared__ float lcv_s[OD_];
    __shared__ float wk_s[K_];
    __shared__ int nns_s[K_];
    __shared__ float anch[3];
    ushort* XTh = smem;                 // 32 x 264
    ushort* XTl = smem + 8448;
    ushort* HTh = smem + 16896;         // 32 x 136
    ushort* HTl = smem + 21248;
    ushort* Ehi = XTh;                  // 32 x 168 (aliases XT; barrier-separated)
    ushort* Elo = XTl;
    float* wEt = (float*)(smem + 16896); // embed scratch aliases HT region
    float* fL  = wEt + 2048;
    float* lcf = fL + 544;

    int gb = blockIdx.x; int b = gb >> 9, g = gb & (G_ - 1);
    int tid = threadIdx.x;
    const float* xb = xyz + (size_t)b * N_ * 3;
    int a = sel[b * G_ + g];
    if (tid < K_) nns_s[tid] = nn[(size_t)gb * K_ + tid];
    if (tid < 3)  anch[tid] = xb[a * 3 + tid];
    __syncthreads();

    // ---- stage embed weights (pre-transposed, coalesced) + gathered feats
    for (int idx = tid; idx < DIN_ * PD_; idx += 256) wEt[idx] = wEtg[idx];
    const float* fb = feat + (size_t)b * N_ * DIN_;
    for (int idx = tid; idx < 33 * DIN_; idx += 256) {
        int k = idx >> 4, j = idx & 15;
        int n = (k < K_) ? nns_s[k] : a;
        fL[idx] = fb[(size_t)n * DIN_ + j];
    }
    __syncthreads();

    const float s_bn = 1.0f / sqrtf(1.0f + 1e-5f);
    // ---- embed, c4-tiled: task = (k, 4 channels). float4 LDS reads, ushort4 writes.
    for (int t = tid; t < 33 * 32; t += 256) {
        int k = t >> 5, c0 = (t & 31) * 4;
        const float* f = &fL[k * DIN_];
        float a0 = 0.f, a1 = 0.f, a2 = 0.f, a3 = 0.f;
#pragma unroll
        for (int i = 0; i < DIN_; ++i) {
            float4 w4 = *(const float4*)&wEt[i * PD_ + c0];
            float fv = f[i];
            a0 += w4.x * fv; a1 += w4.y * fv; a2 += w4.z * fv; a3 += w4.w * fv;
        }
        float4 b4  = *(const float4*)&bE[c0];
        float4 g4  = *(const float4*)&gE[c0];
        float4 be4 = *(const float4*)&beE[c0];
        float o0 = fmaxf((a0 + b4.x) * s_bn * g4.x + be4.x, 0.f);
        float o1 = fmaxf((a1 + b4.y) * s_bn * g4.y + be4.y, 0.f);
        float o2 = fmaxf((a2 + b4.z) * s_bn * g4.z + be4.z, 0.f);
        float o3 = fmaxf((a3 + b4.w) * s_bn * g4.w + be4.w, 0.f);
        if (k < K_) {
            ushort h0, l0, h1, l1, h2, l2, h3, l3;
            bf16_split(o0, h0, l0); bf16_split(o1, h1, l1);
            bf16_split(o2, h2, l2); bf16_split(o3, h3, l3);
            *(ushort4*)&Ehi[k * EST + c0] = make_ushort4(h0, h1, h2, h3);
            *(ushort4*)&Elo[k * EST + c0] = make_ushort4(l0, l1, l2, l3);
        } else {
            *(float4*)&lcf[c0] = make_float4(o0, o1, o2, o3);
        }
    }
    // E cols 128..159: knn xyz (128..130) + zero pad
    for (int idx = tid; idx < K_ * 32; idx += 256) {
        int k = idx >> 5, c = 128 + (idx & 31);
        ushort h = 0, l = 0;
        if (c < 131) { float v = xb[nns_s[k] * 3 + (c - 128)]; bf16_split(v, h, l); }
        Ehi[k * EST + c] = h; Elo[k * EST + c] = l;
    }
    if (tid < K_) {
#pragma clang fp contract(off)
        float sd = stdp[0];
        int n = nns_s[tid];
        float rx = (xb[n * 3]     - anch[0]) / sd - anch[0];
        float ry = (xb[n * 3 + 1] - anch[1]) / sd - anch[1];
        float rz = (xb[n * 3 + 2] - anch[2]) / sd - anch[2];
        float nrm = sqrtf((rx * rx + ry * ry) + rz * rz);
        wk_s[tid] = expf(-0.5f * nrm);
    }
    __syncthreads();
    // ---- anchor-term (f32 exact): lcv[c] = sum_j wta[j][c]*lcf[j]
    {
        float s = 0.f;
        for (int j = 0; j < PD_; ++j) s += wta[j * OD_ + tid] * lcf[j];
        lcv_s[tid] = s;
    }
    __syncthreads();

    int wv = tid >> 6, lane = tid & 63;
    int g16 = lane >> 4, r16 = lane & 15;
    int lane8 = lane * 8;

    // ---- lin1: 4 mtiles x 2 ntiles per wave, K=160, split-3 bf16
    f32x4 accl[4][2];
#pragma unroll
    for (int mt = 0; mt < 4; ++mt) {
        int mc = 64 * wv + 16 * mt + 4 * g16;
        float4 lv = *(const float4*)&lcv_s[mc];
        f32x4 iv = {lv.x, lv.y, lv.z, lv.w};
        accl[mt][0] = iv; accl[mt][1] = iv;
    }
    {
        int eb0 = r16 * EST + g16 * 8;
        int eb1 = (r16 + 16) * EST + g16 * 8;
        for (int kbi = 0; kbi < 5; ++kbi) {
            int kb = kbi * 32;
            short8t eh0 = *(const short8t*)&Ehi[eb0 + kb];
            short8t el0 = *(const short8t*)&Elo[eb0 + kb];
            short8t eh1 = *(const short8t*)&Ehi[eb1 + kb];
            short8t el1 = *(const short8t*)&Elo[eb1 + kb];
#pragma unroll
            for (int mt = 0; mt < 4; ++mt) {
                const ushort* wp = alf + (((4 * wv + mt) * 5 + kbi) << 9) + lane8;
                short8t wh = *(const short8t*)wp;
                short8t wl = *(const short8t*)(wp + 40960);
                accl[mt][0] = MFMA16(wh, eh0, accl[mt][0]);
                accl[mt][1] = MFMA16(wh, eh1, accl[mt][1]);
                accl[mt][0] = MFMA16(wh, el0, accl[mt][0]);
                accl[mt][1] = MFMA16(wh, el1, accl[mt][1]);
                accl[mt][0] = MFMA16(wl, eh0, accl[mt][0]);
                accl[mt][1] = MFMA16(wl, eh1, accl[mt][1]);
            }
        }
    }
    __syncthreads();   // all E reads complete before XT (same memory) is written
    {
        float w0 = wk_s[r16], w1 = wk_s[r16 + 16];
#pragma unroll
        for (int mt = 0; mt < 4; ++mt) {
            int mc = 64 * wv + 16 * mt + 4 * g16;
            float4 gg = *(const float4*)&g_lin1[mc];
            float4 bb = *(const float4*)&be_lin1[mc];
            float ga[4] = {gg.x, gg.y, gg.z, gg.w};
            float ba[4] = {bb.x, bb.y, bb.z, bb.w};
            ushort h0[4], l0[4], h1[4], l1[4];
#pragma unroll
            for (int r = 0; r < 4; ++r) {
                float v0 = fmaxf(accl[mt][0][r] * s_bn * ga[r] + ba[r], 0.f) * w0;
                float v1 = fmaxf(accl[mt][1][r] * s_bn * ga[r] + ba[r], 0.f) * w1;
                bf16_split(v0, h0[r], l0[r]);
                bf16_split(v1, h1[r], l1[r]);
            }
            *(ushort4*)&XTh[r16 * XST2 + mc] = make_ushort4(h0[0], h0[1], h0[2], h0[3]);
            *(ushort4*)&XTl[r16 * XST2 + mc] = make_ushort4(l0[0], l0[1], l0[2], l0[3]);
            *(ushort4*)&XTh[(r16 + 16) * XST2 + mc] = make_ushort4(h1[0], h1[1], h1[2], h1[3]);
            *(ushort4*)&XTl[(r16 + 16) * XST2 + mc] = make_ushort4(l1[0], l1[1], l1[2], l1[3]);
        }
    }
    __syncthreads();

    int xbo0 = r16 * XST2 + g16 * 8;
    int xbo1 = (r16 + 16) * XST2 + g16 * 8;
    int hbo0 = r16 * HST + g16 * 8;
    int hbo1 = (r16 + 16) * HST + g16 * 8;
    const f32x4 zz = {0.f, 0.f, 0.f, 0.f};
    const float inv_k = 1.0f / 32.0f;

    for (int l = 0; l < 2; ++l) {
        // ---- down: 2 mtiles x 2 ntiles per wave, K=256
        f32x4 accd[2][2];
        accd[0][0] = zz; accd[0][1] = zz; accd[1][0] = zz; accd[1][1] = zz;
        for (int kbi = 0; kbi < 8; ++kbi) {
            int kb = kbi * 32;
            short8t xh0 = *(const short8t*)&XTh[xbo0 + kb];
            short8t xl0 = *(const short8t*)&XTl[xbo0 + kb];
            short8t xh1 = *(const short8t*)&XTh[xbo1 + kb];
            short8t xl1 = *(const short8t*)&XTl[xbo1 + kb];
#pragma unroll
            for (int mt = 0; mt < 2; ++mt) {
                const ushort* wp = adf + (((l * 8 + (2 * wv + mt)) * 8 + kbi) << 9) + lane8;
                short8t wh = *(const short8t*)wp;
                short8t wl = *(const short8t*)(wp + 65536);
                accd[mt][0] = MFMA16(wh, xh0, accd[mt][0]);
                accd[mt][1] = MFMA16(wh, xh1, accd[mt][1]);
                accd[mt][0] = MFMA16(wh, xl0, accd[mt][0]);
                accd[mt][1] = MFMA16(wh, xl1, accd[mt][1]);
                accd[mt][0] = MFMA16(wl, xh0, accd[mt][0]);
                accd[mt][1] = MFMA16(wl, xh1, accd[mt][1]);
            }
        }
#pragma unroll
        for (int mt = 0; mt < 2; ++mt) {
            int mc = 32 * wv + 16 * mt + 4 * g16;
            float4 db = *(const float4*)&down_b[l * MD_ + mc];
            float4 gv = *(const float4*)&gd[l * MD_ + mc];
            float4 bv = *(const float4*)&bd[l * MD_ + mc];
            float dba[4] = {db.x, db.y, db.z, db.w};
            float gva[4] = {gv.x, gv.y, gv.z, gv.w};
            float bva[4] = {bv.x, bv.y, bv.z, bv.w};
            ushort h0[4], l0[4], h1[4], l1[4];
#pragma unroll
            for (int r = 0; r < 4; ++r) {
                float v0 = fmaxf((accd[mt][0][r] + dba[r]) * s_bn * gva[r] + bva[r], 0.f);
                float v1 = fmaxf((accd[mt][1][r] + dba[r]) * s_bn * gva[r] + bva[r], 0.f);
                bf16_split(v0, h0[r], l0[r]);
                bf16_split(v1, h1[r], l1[r]);
            }
            *(ushort4*)&HTh[r16 * HST + mc] = make_ushort4(h0[0], h0[1], h0[2], h0[3]);
            *(ushort4*)&HTl[r16 * HST + mc] = make_ushort4(l0[0], l0[1], l0[2], l0[3]);
            *(ushort4*)&HTh[(r16 + 16) * HST + mc] = make_ushort4(h1[0], h1[1], h1[2], h1[3]);
            *(ushort4*)&HTl[(r16 + 16) * HST + mc] = make_ushort4(l1[0], l1[1], l1[2], l1[3]);
        }
        __syncthreads();

        // ---- up: 4 mtiles x 2 ntiles per wave, K=128
        f32x4 accu[4][2];
#pragma unroll
        for (int mt = 0; mt < 4; ++mt) { accu[mt][0] = zz; accu[mt][1] = zz; }
        for (int kbi = 0; kbi < 4; ++kbi) {
            int kb = kbi * 32;
            short8t hh0 = *(const short8t*)&HTh[hbo0 + kb];
            short8t hl0 = *(const short8t*)&HTl[hbo0 + kb];
            short8t hh1 = *(const short8t*)&HTh[hbo1 + kb];
            short8t hl1 = *(const short8t*)&HTl[hbo1 + kb];
#pragma unroll
            for (int mt = 0; mt < 4; ++mt) {
                const ushort* wp = auf + (((l * 16 + (4 * wv + mt)) * 4 + kbi) << 9) + lane8;
                short8t wh = *(const short8t*)wp;
                short8t wl = *(const short8t*)(wp + 65536);
                accu[mt][0] = MFMA16(wh, hh0, accu[mt][0]);
                accu[mt][1] = MFMA16(wh, hh1, accu[mt][1]);
                accu[mt][0] = MFMA16(wh, hl0, accu[mt][0]);
                accu[mt][1] = MFMA16(wh, hl1, accu[mt][1]);
                accu[mt][0] = MFMA16(wl, hh0, accu[mt][0]);
                accu[mt][1] = MFMA16(wl, hh1, accu[mt][1]);
            }
        }
        // ---- up epilogue: residual add
#pragma unroll
        for (int mt = 0; mt < 4; ++mt) {
            int mc = 64 * wv + 16 * mt + 4 * g16;
            float4 ub = *(const float4*)&up_b[l * OD_ + mc];
            float4 gv = *(const float4*)&gu[l * OD_ + mc];
            float4 bv = *(const float4*)&bu[l * OD_ + mc];
            float uba[4] = {ub.x, ub.y, ub.z, ub.w};
            float gva[4] = {gv.x, gv.y, gv.z, gv.w};
            float bva[4] = {bv.x, bv.y, bv.z, bv.w};
            ushort4 xh0 = *(const ushort4*)&XTh[r16 * XST2 + mc];
            ushort4 xl0 = *(const ushort4*)&XTl[r16 * XST2 + mc];
            ushort4 xh1 = *(const ushort4*)&XTh[(r16 + 16) * XST2 + mc];
            ushort4 xl1 = *(const ushort4*)&XTl[(r16 + 16) * XST2 + mc];
            ushort xha0[4] = {xh0.x, xh0.y, xh0.z, xh0.w};
            ushort xla0[4] = {xl0.x, xl0.y, xl0.z, xl0.w};
            ushort xha1[4] = {xh1.x, xh1.y, xh1.z, xh1.w};
            ushort xla1[4] = {xl1.x, xl1.y, xl1.z, xl1.w};
            float nx0[4], nx1[4];
#pragma unroll
            for (int r = 0; r < 4; ++r) {
                float xf0 = __uint_as_float((unsigned)xha0[r] << 16) + __uint_as_float((unsigned)xla0[r] << 16);
                float xf1 = __uint_as_float((unsigned)xha1[r] << 16) + __uint_as_float((unsigned)xla1[r] << 16);
                float v0 = (accu[mt][0][r] + uba[r]) * s_bn * gva[r] + bva[r];
                float v1 = (accu[mt][1][r] + uba[r]) * s_bn * gva[r] + bva[r];
                nx0[r] = fmaxf(v0 + xf0, 0.f);
                nx1[r] = fmaxf(v1 + xf1, 0.f);
            }
            if (l == 0) {
                ushort h0[4], l0[4], h1[4], l1[4];
#pragma unroll
                for (int r = 0; r < 4; ++r) {
                    bf16_split(nx0[r], h0[r], l0[r]);
                    bf16_split(nx1[r], h1[r], l1[r]);
                }
                *(ushort4*)&XTh[r16 * XST2 + mc] = make_ushort4(h0[0], h0[1], h0[2], h0[3]);
                *(ushort4*)&XTl[r16 * XST2 + mc] = make_ushort4(l0[0], l0[1], l0[2], l0[3]);
                *(ushort4*)&XTh[(r16 + 16) * XST2 + mc] = make_ushort4(h1[0], h1[1], h1[2], h1[3]);
                *(ushort4*)&XTl[(r16 + 16) * XST2 + mc] = make_ushort4(l1[0], l1[1], l1[2], l1[3]);
            } else {
                // final: max + mean over 32 pts (16 lanes x 2 ntiles)
#pragma unroll
                for (int r = 0; r < 4; ++r) {
                    float mx = fmaxf(nx0[r], nx1[r]);
                    float sm = nx0[r] + nx1[r];
#pragma unroll
                    for (int off = 1; off < 16; off <<= 1) {
                        mx = fmaxf(mx, __shfl_xor(mx, off));
                        sm += __shfl_xor(sm, off);
                    }
                    if (r16 == 0)
                        out[((size_t)(b * OD_ + mc + r)) * G_ + g] = mx + sm * inv_k;
                }
            }
        }
        __syncthreads();
    }
}

extern "C" void kernel_launch(void* const* d_in, const int* in_sizes, int n_in,
                              void* d_out, int out_size, void* d_ws, size_t ws_size,
                              hipStream_t stream) {
    const float* xyz     = (const float*)d_in[0];
    const float* feat    = (const float*)d_in[1];
    const float* w_embed = (const float*)d_in[2];
    const float* b_embed = (const float*)d_in[3];
    const float* g_embed = (const float*)d_in[4];
    const float* be_embed= (const float*)d_in[5];
    const float* w_lin1  = (const float*)d_in[6];
    const float* g_lin1  = (const float*)d_in[7];
    const float* be_lin1 = (const float*)d_in[8];
    const float* down_w  = (const float*)d_in[9];
    const float* down_b  = (const float*)d_in[10];
    const float* gd      = (const float*)d_in[11];
    const float* bd      = (const float*)d_in[12];
    const float* up_w    = (const float*)d_in[13];
    const float* up_b    = (const float*)d_in[14];
    const float* gu      = (const float*)d_in[15];
    const float* bu      = (const float*)d_in[16];
    float* out = (float*)d_out;

    // workspace carve (~1.38 MB)
    char* w = (char*)d_ws;
    float* wta   = (float*)w;  w += PD_ * OD_ * 4;           // 131072
    float* wEtg  = (float*)w;  w += DIN_ * PD_ * 4;          // 8192
    ushort* alf  = (ushort*)w; w += 2 * 40960 * 2;           // 163840
    ushort* adf  = (ushort*)w; w += 2 * 65536 * 2;           // 262144
    ushort* auf  = (ushort*)w; w += 2 * 65536 * 2;           // 262144
    int* sel     = (int*)w;    w += B_ * G_ * 4;             // 16384
    int* nn      = (int*)w;    w += B_ * G_ * K_ * 4;        // 524288
    double* acc  = (double*)w; w += 16;
    float* stdp  = (float*)w;

    hipMemsetAsync(acc, 0, 2 * sizeof(double), stream);
    prep_kernel<<<256, 256, 0, stream>>>(w_lin1, down_w, up_w, w_embed,
                                         wta, wEtg, alf, adf, auf);
    fps_kernel<<<B_, 512, 0, stream>>>(xyz, sel);
    knn_kernel<<<B_ * G_, 256, 0, stream>>>(xyz, sel, nn);
    std_acc_kernel<<<256, 256, 0, stream>>>(xyz, sel, nn, acc);
    std_fin_kernel<<<1, 1, 0, stream>>>(acc, stdp);
    group_kernel<<<B_ * G_, 256, 0, stream>>>(xyz, feat, wEtg, b_embed, g_embed, be_embed,
        sel, nn, wta, alf, adf, auf, g_lin1, be_lin1, down_b, gd, bd, up_b, gu, bu, stdp, out);
}

// Round 10
// 947.886 us; speedup vs baseline: 1.1623x; 1.1623x over previous
//
#include <hip/hip_runtime.h>

#define B_ 8
#define N_ 8192
#define DIN_ 16
#define G_ 512
#define K_ 32
#define OD_ 256
#define PD_ 128
#define MD_ 128
#define CE_ 259
#define EST 168    // E row stride (bf16 elems)
#define XST2 264   // x tile row stride
#define HST 136    // h tile row stride
#define AL1K 160   // lin1 K padded 131->160

typedef __attribute__((ext_vector_type(8))) short short8t;
typedef __attribute__((ext_vector_type(4))) float f32x4;
typedef __attribute__((ext_vector_type(2))) float v2f;
#define MFMA16(a, b, c) __builtin_amdgcn_mfma_f32_16x16x32_bf16((a), (b), (c), 0, 0, 0)

__device__ __forceinline__ ushort bf16_rne(float x) {
    unsigned u = __float_as_uint(x);
    return (ushort)((u + 0x7FFFu + ((u >> 16) & 1u)) >> 16);
}
__device__ __forceinline__ void bf16_split(float x, ushort& h, ushort& l) {
    h = bf16_rne(x);
    float hf = __uint_as_float((unsigned)h << 16);
    l = bf16_rne(x - hf);
}

// ---- DPP wave64 reductions (VALU-only)
#define DPP_STEP_MAXF(x, ctrl) { int _t = __builtin_amdgcn_update_dpp(            \
        __float_as_int(x), __float_as_int(x), (ctrl), 0xF, 0xF, false);           \
        (x) = fmaxf((x), __int_as_float(_t)); }
#define DPP_STEP_MINF(x, ctrl) { int _t = __builtin_amdgcn_update_dpp(            \
        __float_as_int(x), __float_as_int(x), (ctrl), 0xF, 0xF, false);           \
        (x) = fminf((x), __int_as_float(_t)); }
#define DPP_STEP_MINU(x, ctrl) { int _t = __builtin_amdgcn_update_dpp(            \
        (int)(x), (int)(x), (ctrl), 0xF, 0xF, false);                             \
        unsigned _u = (unsigned)_t; (x) = ((x) < _u) ? (x) : _u; }

__device__ __forceinline__ float wave_max_f32(float x) {
    DPP_STEP_MAXF(x, 0x121); DPP_STEP_MAXF(x, 0x122);
    DPP_STEP_MAXF(x, 0x124); DPP_STEP_MAXF(x, 0x128);
    DPP_STEP_MAXF(x, 0x142); DPP_STEP_MAXF(x, 0x143);
    return __int_as_float(__builtin_amdgcn_readlane(__float_as_int(x), 63));
}
__device__ __forceinline__ float wave_min_f32(float x) {
    DPP_STEP_MINF(x, 0x121); DPP_STEP_MINF(x, 0x122);
    DPP_STEP_MINF(x, 0x124); DPP_STEP_MINF(x, 0x128);
    DPP_STEP_MINF(x, 0x142); DPP_STEP_MINF(x, 0x143);
    return __int_as_float(__builtin_amdgcn_readlane(__float_as_int(x), 63));
}
__device__ __forceinline__ unsigned wave_min_u32(unsigned x) {
    DPP_STEP_MINU(x, 0x121); DPP_STEP_MINU(x, 0x122);
    DPP_STEP_MINU(x, 0x124); DPP_STEP_MINU(x, 0x128);
    DPP_STEP_MINU(x, 0x142); DPP_STEP_MINU(x, 0x143);
    return (unsigned)__builtin_amdgcn_readlane((int)x, 63);
}

// ---------------- prep: fragment-ordered bf16 hi/lo weight planes ----------------
__global__ __launch_bounds__(256)
void prep_kernel(const float* __restrict__ w_lin1, const float* __restrict__ down_w,
                 const float* __restrict__ up_w, const float* __restrict__ w_embed,
                 float* __restrict__ wta, float* __restrict__ wEtg,
                 ushort* __restrict__ alf, ushort* __restrict__ adf,
                 ushort* __restrict__ auf) {
    int i = blockIdx.x * blockDim.x + threadIdx.x;
    if (i < PD_ * OD_) {                        // wta[j][c] = w_lin1[c][131+j]
        int j = i >> 8, c = i & 255;
        wta[i] = w_lin1[c * CE_ + 131 + j];
    }
    if (i < DIN_ * PD_) {                       // wEtg[r][c] = w_embed[c][r]
        int r = i >> 7, c = i & 127;
        wEtg[i] = w_embed[c * DIN_ + r];
    }
    if (i < 5120) {                             // alf: mtile in [0,16), kbi in [0,5)
        int lane = i & 63, t = i >> 6;
        int kbi = t % 5, mtile = t / 5;
        int m = mtile * 16 + (lane & 15), g16 = lane >> 4;
        int dst = i * 8;
#pragma unroll
        for (int j = 0; j < 8; ++j) {
            int k = kbi * 32 + g16 * 8 + j;
            float v = (k < 131) ? w_lin1[m * CE_ + k] : 0.f;
            ushort h, l; bf16_split(v, h, l);
            alf[dst + j] = h; alf[dst + j + 40960] = l;
        }
    }
    if (i < 8192) {                             // adf: t = ((l*8+mtile)*8+kbi)
        int lane = i & 63, t = i >> 6;
        int kbi = t & 7, mtile = (t >> 3) & 7, l = t >> 6;
        int m = mtile * 16 + (lane & 15), g16 = lane >> 4;
        int dst = i * 8;
#pragma unroll
        for (int j = 0; j < 8; ++j) {
            int k = kbi * 32 + g16 * 8 + j;
            float v = down_w[(l * MD_ + m) * OD_ + k];
            ushort h, lo; bf16_split(v, h, lo);
            adf[dst + j] = h; adf[dst + j + 65536] = lo;
        }
    }
    if (i < 8192) {                             // auf: t = ((l*16+mtile)*4+kbi)
        int lane = i & 63, t = i >> 6;
        int kbi = t & 3, mtile = (t >> 2) & 15, l = t >> 6;
        int m = mtile * 16 + (lane & 15), g16 = lane >> 4;
        int dst = i * 8;
#pragma unroll
        for (int j = 0; j < 8; ++j) {
            int k = kbi * 32 + g16 * 8 + j;
            float v = up_w[(l * OD_ + m) * MD_ + k];
            ushort h, lo; bf16_split(v, h, lo);
            auf[dst + j] = h; auf[dst + j + 65536] = lo;
        }
    }
}

// ---------------- FPS: 512 thr / 8 waves; packed-f32 updates, scalar index chain ----------------
__global__ __launch_bounds__(512)
void fps_kernel(const float* __restrict__ xyz, int* __restrict__ sel) {
#pragma clang fp contract(off)
    __shared__ float sx[N_], sy[N_], sz[N_];
    __shared__ unsigned long long wred[2][8];
    __shared__ int sel_s[G_];
    int b = blockIdx.x, tid = threadIdx.x;
    const float* xb = xyz + (size_t)b * N_ * 3;
    for (int i = tid; i < N_; i += 512) {
        sx[i] = xb[i * 3]; sy[i] = xb[i * 3 + 1]; sz[i] = xb[i * 3 + 2];
    }
    __syncthreads();
    // 16 pts/thread as 8 float2 pairs: pair p elem e -> idx = tid + (2p+e)*512
    v2f px2[8], py2[8], pz2[8], mind2[8];
    float bv = -1.f; int bj = 0;
#pragma unroll
    for (int p = 0; p < 8; ++p) {
        int i0 = tid + (2 * p) * 512, i1 = tid + (2 * p + 1) * 512;
        px2[p] = (v2f){sx[i0], sx[i1]};
        py2[p] = (v2f){sy[i0], sy[i1]};
        pz2[p] = (v2f){sz[i0], sz[i1]};
        mind2[p] = (v2f){1e10f, 1e10f};
        v2f ss = px2[p] * px2[p] + py2[p] * py2[p];
        ss = ss + pz2[p] * pz2[p];
        if (ss[0] > bv) { bv = ss[0]; bj = 2 * p; }
        if (ss[1] > bv) { bv = ss[1]; bj = 2 * p + 1; }
    }
    int bi = tid + bj * 512;
    int wv = tid >> 6;
    {
        float wm = wave_max_f32(bv);
        unsigned mi = (bv == wm) ? (unsigned)bi : 0xFFFFFFFFu;
        unsigned wi = wave_min_u32(mi);
        if ((tid & 63) == 0)
            wred[0][wv] = ((unsigned long long)__float_as_uint(wm) << 32)
                        | (unsigned long long)(0xFFFFFFFFu - wi);
    }
    __syncthreads();
    unsigned long long best = wred[0][0];
#pragma unroll
    for (int i = 1; i < 8; ++i) { unsigned long long v = wred[0][i]; if (v > best) best = v; }
    int cur = (int)(0xFFFFFFFFu - (unsigned)(best & 0xFFFFFFFFull));

    for (int it = 0; it < G_; ++it) {
        if (tid == 0) sel_s[it] = cur;
        float cx = sx[cur], cy = sy[cur], cz = sz[cur];
        v2f cx2 = (v2f){cx, cx}, cy2 = (v2f){cy, cy}, cz2 = (v2f){cz, cz};
        // packed distance + min update (v_pk_*: bit-identical IEEE per half)
#pragma unroll
        for (int p = 0; p < 8; ++p) {
            v2f dx = px2[p] - cx2, dy = py2[p] - cy2, dz = pz2[p] - cz2;
            v2f d = dx * dx + dy * dy;
            d = d + dz * dz;
            mind2[p] = __builtin_elementwise_min(mind2[p], d);
        }
        // scalar argmax chain, first-index ties (strict >), inline-const bj
        bv = -1.f; bj = 0;
#pragma unroll
        for (int j = 0; j < 16; ++j) {
            float m = mind2[j >> 1][j & 1];
            if (m > bv) { bv = m; bj = j; }
        }
        bi = tid + bj * 512;
        float wm = wave_max_f32(bv);
        unsigned mi = (bv == wm) ? (unsigned)bi : 0xFFFFFFFFu;
        unsigned wi = wave_min_u32(mi);
        int pb = (it + 1) & 1;
        if ((tid & 63) == 0)
            wred[pb][wv] = ((unsigned long long)__float_as_uint(wm) << 32)
                         | (unsigned long long)(0xFFFFFFFFu - wi);
        __syncthreads();
        best = wred[pb][0];
#pragma unroll
        for (int i = 1; i < 8; ++i) { unsigned long long v = wred[pb][i]; if (v > best) best = v; }
        cur = (int)(0xFFFFFFFFu - (unsigned)(best & 0xFFFFFFFFull));
    }
    __syncthreads();
    sel[b * G_ + tid] = sel_s[tid];
}

// ---------------- KNN: DPP argmin; picks buffered in LDS ----------------
__global__ __launch_bounds__(256)
void knn_kernel(const float* __restrict__ xyz, const int* __restrict__ sel,
                int* __restrict__ nn) {
#pragma clang fp contract(off)
    __shared__ float dld[N_];
    __shared__ unsigned long long wred[2][4];
    __shared__ int nn_s[K_];
    int gb = blockIdx.x; int b = gb >> 9, s = gb & (G_ - 1);
    const float* xb = xyz + (size_t)b * N_ * 3;
    int q = sel[b * G_ + s];
    float qx = xb[q * 3], qy = xb[q * 3 + 1], qz = xb[q * 3 + 2];
    float qq = (qx * qx + qy * qy) + qz * qz;
    int tid = threadIdx.x;
    const float FINF = __builtin_inff();
    float lv = FINF; int li = tid;
#pragma unroll 4
    for (int j = 0; j < 32; ++j) {
        int n = tid + j * 256;
        float rx = xb[n * 3], ry = xb[n * 3 + 1], rz = xb[n * 3 + 2];
        float rr = (rx * rx + ry * ry) + rz * rz;
        float dt = (qx * rx + qy * ry) + qz * rz;
        float d = (qq + rr) - 2.0f * dt;
        d = fmaxf(d, 0.f);
        dld[n] = d;
        if (d < lv) { lv = d; li = n; }
    }
    {
        float wm = wave_min_f32(lv);
        unsigned mi = (lv == wm) ? (unsigned)li : 0xFFFFFFFFu;
        unsigned wi = wave_min_u32(mi);
        if ((tid & 63) == 0)
            wred[0][tid >> 6] = ((unsigned long long)__float_as_uint(wm) << 32)
                              | (unsigned long long)wi;
    }
    __syncthreads();
    unsigned long long best = wred[0][0];
#pragma unroll
    for (int i = 1; i < 4; ++i) { unsigned long long v = wred[0][i]; if (v < best) best = v; }
    int win = (int)(best & 0xFFFFFFFFull);

    for (int t = 0; t < K_; ++t) {
        if (tid == 0) nn_s[t] = win;
        if ((win & 255) == tid) {
            dld[win] = FINF;
            lv = FINF; li = tid;
            for (int j = 0; j < 32; ++j) {
                float d = dld[tid + j * 256];
                if (d < lv) { lv = d; li = tid + j * 256; }
            }
        }
        float wm = wave_min_f32(lv);
        unsigned mi = (lv == wm) ? (unsigned)li : 0xFFFFFFFFu;
        unsigned wi = wave_min_u32(mi);
        int pb = (t + 1) & 1;
        if ((tid & 63) == 0)
            wred[pb][tid >> 6] = ((unsigned long long)__float_as_uint(wm) << 32)
                               | (unsigned long long)wi;
        __syncthreads();
        best = wred[pb][0];
#pragma unroll
        for (int i = 1; i < 4; ++i) { unsigned long long v = wred[pb][i]; if (v < best) best = v; }
        win = (int)(best & 0xFFFFFFFFull);
    }
    if (tid < K_) nn[(size_t)gb * K_ + tid] = nn_s[tid];
}

// ---------------- global std (ddof=1) ----------------
__global__ void std_acc_kernel(const float* __restrict__ xyz, const int* __restrict__ sel,
                               const int* __restrict__ nn, double* __restrict__ acc) {
    int tot = B_ * G_ * K_;
    int stride = gridDim.x * blockDim.x;
    double ls = 0.0, lss = 0.0;
    for (int idx = blockIdx.x * blockDim.x + threadIdx.x; idx < tot; idx += stride) {
        int b = idx >> 14; int g = (idx >> 5) & (G_ - 1);
        int n = nn[idx]; int a = sel[b * G_ + g];
        const float* xb = xyz + (size_t)b * N_ * 3;
#pragma unroll
        for (int c = 0; c < 3; ++c) {
            float v = xb[n * 3 + c] - xb[a * 3 + c];
            ls += (double)v; lss += (double)v * (double)v;
        }
    }
#pragma unroll
    for (int off = 32; off > 0; off >>= 1) {
        ls += __shfl_down(ls, off); lss += __shfl_down(lss, off);
    }
    if ((threadIdx.x & 63) == 0) { atomicAdd(acc, ls); atomicAdd(acc + 1, lss); }
}

__global__ void std_fin_kernel(const double* __restrict__ acc, float* __restrict__ stdp) {
    double s = acc[0], ss = acc[1];
    double M = (double)(B_ * G_ * K_ * 3);
    double var = (ss - s * s / M) / (M - 1.0);
    stdp[0] = (float)sqrt(var) + 1e-5f;
}

// ---------------- fused per-group pipeline, MFMA split-bf16 GEMMs ----------------
__global__ __launch_bounds__(256, 3)
void group_kernel(const float* __restrict__ xyz, const float* __restrict__ feat,
                  const float* __restrict__ wEtg, const float* __restrict__ bE,
                  const float* __restrict__ gE, const float* __restrict__ beE,
                  const int* __restrict__ sel, const int* __restrict__ nn,
                  const float* __restrict__ wta,
                  const ushort* __restrict__ alf, const ushort* __restrict__ adf,
                  const ushort* __restrict__ auf,
                  const float* __restrict__ g_lin1, const float* __restrict__ be_lin1,
                  const float* __restrict__ down_b, const float* __restrict__ gd,
                  const float* __restrict__ bd,
                  const float* __restrict__ up_b, const float* __restrict__ gu,
                  const float* __restrict__ bu,
                  const float* __restrict__ stdp, float* __restrict__ out) {
    __shared__ __align__(16) ushort smem[25600];
    __shared__ float lcv_s[OD_];
    __shared__ float wk_s[K_];
    __shared__ int nns_s[K_];
    __shared__ float anch[3];
    ushort* XTh = smem;                 // 32 x 264
    ushort* XTl = smem + 8448;
    ushort* HTh = smem + 16896;         // 32 x 136
    ushort* HTl = smem + 21248;
    ushort* Ehi = XTh;                  // 32 x 168 (aliases XT; barrier-separated)
    ushort* Elo = XTl;
    float* wEt = (float*)(smem + 16896); // embed scratch aliases HT region
    float* fL  = wEt + 2048;
    float* lcf = fL + 544;

    int gb = blockIdx.x; int b = gb >> 9, g = gb & (G_ - 1);
    int tid = threadIdx.x;
    const float* xb = xyz + (size_t)b * N_ * 3;
    int a = sel[b * G_ + g];
    if (tid < K_) nns_s[tid] = nn[(size_t)gb * K_ + tid];
    if (tid < 3)  anch[tid] = xb[a * 3 + tid];
    __syncthreads();

    // ---- stage embed weights (pre-transposed, coalesced) + gathered feats
    for (int idx = tid; idx < DIN_ * PD_; idx += 256) wEt[idx] = wEtg[idx];
    const float* fb = feat + (size_t)b * N_ * DIN_;
    for (int idx = tid; idx < 33 * DIN_; idx += 256) {
        int k = idx >> 4, j = idx & 15;
        int n = (k < K_) ? nns_s[k] : a;
        fL[idx] = fb[(size_t)n * DIN_ + j];
    }
    __syncthreads();

    const float s_bn = 1.0f / sqrtf(1.0f + 1e-5f);
    // ---- embed, c4-tiled: task = (k, 4 channels). float4 LDS reads, ushort4 writes.
    for (int t = tid; t < 33 * 32; t += 256) {
        int k = t >> 5, c0 = (t & 31) * 4;
        const float* f = &fL[k * DIN_];
        float a0 = 0.f, a1 = 0.f, a2 = 0.f, a3 = 0.f;
#pragma unroll
        for (int i = 0; i < DIN_; ++i) {
            float4 w4 = *(const float4*)&wEt[i * PD_ + c0];
            float fv = f[i];
            a0 += w4.x * fv; a1 += w4.y * fv; a2 += w4.z * fv; a3 += w4.w * fv;
        }
        float4 b4  = *(const float4*)&bE[c0];
        float4 g4  = *(const float4*)&gE[c0];
        float4 be4 = *(const float4*)&beE[c0];
        float o0 = fmaxf((a0 + b4.x) * s_bn * g4.x + be4.x, 0.f);
        float o1 = fmaxf((a1 + b4.y) * s_bn * g4.y + be4.y, 0.f);
        float o2 = fmaxf((a2 + b4.z) * s_bn * g4.z + be4.z, 0.f);
        float o3 = fmaxf((a3 + b4.w) * s_bn * g4.w + be4.w, 0.f);
        if (k < K_) {
            ushort h0, l0, h1, l1, h2, l2, h3, l3;
            bf16_split(o0, h0, l0); bf16_split(o1, h1, l1);
            bf16_split(o2, h2, l2); bf16_split(o3, h3, l3);
            *(ushort4*)&Ehi[k * EST + c0] = make_ushort4(h0, h1, h2, h3);
            *(ushort4*)&Elo[k * EST + c0] = make_ushort4(l0, l1, l2, l3);
        } else {
            *(float4*)&lcf[c0] = make_float4(o0, o1, o2, o3);
        }
    }
    // E cols 128..159: knn xyz (128..130) + zero pad
    for (int idx = tid; idx < K_ * 32; idx += 256) {
        int k = idx >> 5, c = 128 + (idx & 31);
        ushort h = 0, l = 0;
        if (c < 131) { float v = xb[nns_s[k] * 3 + (c - 128)]; bf16_split(v, h, l); }
        Ehi[k * EST + c] = h; Elo[k * EST + c] = l;
    }
    if (tid < K_) {
#pragma clang fp contract(off)
        float sd = stdp[0];
        int n = nns_s[tid];
        float rx = (xb[n * 3]     - anch[0]) / sd - anch[0];
        float ry = (xb[n * 3 + 1] - anch[1]) / sd - anch[1];
        float rz = (xb[n * 3 + 2] - anch[2]) / sd - anch[2];
        float nrm = sqrtf((rx * rx + ry * ry) + rz * rz);
        wk_s[tid] = expf(-0.5f * nrm);
    }
    __syncthreads();
    // ---- anchor-term (f32 exact): lcv[c] = sum_j wta[j][c]*lcf[j]
    {
        float s = 0.f;
        for (int j = 0; j < PD_; ++j) s += wta[j * OD_ + tid] * lcf[j];
        lcv_s[tid] = s;
    }
    __syncthreads();

    int wv = tid >> 6, lane = tid & 63;
    int g16 = lane >> 4, r16 = lane & 15;
    int lane8 = lane * 8;

    // ---- lin1: 4 mtiles x 2 ntiles per wave, K=160, split-3 bf16
    f32x4 accl[4][2];
#pragma unroll
    for (int mt = 0; mt < 4; ++mt) {
        int mc = 64 * wv + 16 * mt + 4 * g16;
        float4 lv = *(const float4*)&lcv_s[mc];
        f32x4 iv = {lv.x, lv.y, lv.z, lv.w};
        accl[mt][0] = iv; accl[mt][1] = iv;
    }
    {
        int eb0 = r16 * EST + g16 * 8;
        int eb1 = (r16 + 16) * EST + g16 * 8;
        for (int kbi = 0; kbi < 5; ++kbi) {
            int kb = kbi * 32;
            short8t eh0 = *(const short8t*)&Ehi[eb0 + kb];
            short8t el0 = *(const short8t*)&Elo[eb0 + kb];
            short8t eh1 = *(const short8t*)&Ehi[eb1 + kb];
            short8t el1 = *(const short8t*)&Elo[eb1 + kb];
#pragma unroll
            for (int mt = 0; mt < 4; ++mt) {
                const ushort* wp = alf + (((4 * wv + mt) * 5 + kbi) << 9) + lane8;
                short8t wh = *(const short8t*)wp;
                short8t wl = *(const short8t*)(wp + 40960);
                accl[mt][0] = MFMA16(wh, eh0, accl[mt][0]);
                accl[mt][1] = MFMA16(wh, eh1, accl[mt][1]);
                accl[mt][0] = MFMA16(wh, el0, accl[mt][0]);
                accl[mt][1] = MFMA16(wh, el1, accl[mt][1]);
                accl[mt][0] = MFMA16(wl, eh0, accl[mt][0]);
                accl[mt][1] = MFMA16(wl, eh1, accl[mt][1]);
            }
        }
    }
    __syncthreads();   // all E reads complete before XT (same memory) is written
    {
        float w0 = wk_s[r16], w1 = wk_s[r16 + 16];
#pragma unroll
        for (int mt = 0; mt < 4; ++mt) {
            int mc = 64 * wv + 16 * mt + 4 * g16;
            float4 gg = *(const float4*)&g_lin1[mc];
            float4 bb = *(const float4*)&be_lin1[mc];
            float ga[4] = {gg.x, gg.y, gg.z, gg.w};
            float ba[4] = {bb.x, bb.y, bb.z, bb.w};
            ushort h0[4], l0[4], h1[4], l1[4];
#pragma unroll
            for (int r = 0; r < 4; ++r) {
                float v0 = fmaxf(accl[mt][0][r] * s_bn * ga[r] + ba[r], 0.f) * w0;
                float v1 = fmaxf(accl[mt][1][r] * s_bn * ga[r] + ba[r], 0.f) * w1;
                bf16_split(v0, h0[r], l0[r]);
                bf16_split(v1, h1[r], l1[r]);
            }
            *(ushort4*)&XTh[r16 * XST2 + mc] = make_ushort4(h0[0], h0[1], h0[2], h0[3]);
            *(ushort4*)&XTl[r16 * XST2 + mc] = make_ushort4(l0[0], l0[1], l0[2], l0[3]);
            *(ushort4*)&XTh[(r16 + 16) * XST2 + mc] = make_ushort4(h1[0], h1[1], h1[2], h1[3]);
            *(ushort4*)&XTl[(r16 + 16) * XST2 + mc] = make_ushort4(l1[0], l1[1], l1[2], l1[3]);
        }
    }
    __syncthreads();

    int xbo0 = r16 * XST2 + g16 * 8;
    int xbo1 = (r16 + 16) * XST2 + g16 * 8;
    int hbo0 = r16 * HST + g16 * 8;
    int hbo1 = (r16 + 16) * HST + g16 * 8;
    const f32x4 zz = {0.f, 0.f, 0.f, 0.f};
    const float inv_k = 1.0f / 32.0f;

    for (int l = 0; l < 2; ++l) {
        // ---- down: 2 mtiles x 2 ntiles per wave, K=256
        f32x4 accd[2][2];
        accd[0][0] = zz; accd[0][1] = zz; accd[1][0] = zz; accd[1][1] = zz;
        for (int kbi = 0; kbi < 8; ++kbi) {
            int kb = kbi * 32;
            short8t xh0 = *(const short8t*)&XTh[xbo0 + kb];
            short8t xl0 = *(const short8t*)&XTl[xbo0 + kb];
            short8t xh1 = *(const short8t*)&XTh[xbo1 + kb];
            short8t xl1 = *(const short8t*)&XTl[xbo1 + kb];
#pragma unroll
            for (int mt = 0; mt < 2; ++mt) {
                const ushort* wp = adf + (((l * 8 + (2 * wv + mt)) * 8 + kbi) << 9) + lane8;
                short8t wh = *(const short8t*)wp;
                short8t wl = *(const short8t*)(wp + 65536);
                accd[mt][0] = MFMA16(wh, xh0, accd[mt][0]);
                accd[mt][1] = MFMA16(wh, xh1, accd[mt][1]);
                accd[mt][0] = MFMA16(wh, xl0, accd[mt][0]);
                accd[mt][1] = MFMA16(wh, xl1, accd[mt][1]);
                accd[mt][0] = MFMA16(wl, xh0, accd[mt][0]);
                accd[mt][1] = MFMA16(wl, xh1, accd[mt][1]);
            }
        }
#pragma unroll
        for (int mt = 0; mt < 2; ++mt) {
            int mc = 32 * wv + 16 * mt + 4 * g16;
            float4 db = *(const float4*)&down_b[l * MD_ + mc];
            float4 gv = *(const float4*)&gd[l * MD_ + mc];
            float4 bv = *(const float4*)&bd[l * MD_ + mc];
            float dba[4] = {db.x, db.y, db.z, db.w};
            float gva[4] = {gv.x, gv.y, gv.z, gv.w};
            float bva[4] = {bv.x, bv.y, bv.z, bv.w};
            ushort h0[4], l0[4], h1[4], l1[4];
#pragma unroll
            for (int r = 0; r < 4; ++r) {
                float v0 = fmaxf((accd[mt][0][r] + dba[r]) * s_bn * gva[r] + bva[r], 0.f);
                float v1 = fmaxf((accd[mt][1][r] + dba[r]) * s_bn * gva[r] + bva[r], 0.f);
                bf16_split(v0, h0[r], l0[r]);
                bf16_split(v1, h1[r], l1[r]);
            }
            *(ushort4*)&HTh[r16 * HST + mc] = make_ushort4(h0[0], h0[1], h0[2], h0[3]);
            *(ushort4*)&HTl[r16 * HST + mc] = make_ushort4(l0[0], l0[1], l0[2], l0[3]);
            *(ushort4*)&HTh[(r16 + 16) * HST + mc] = make_ushort4(h1[0], h1[1], h1[2], h1[3]);
            *(ushort4*)&HTl[(r16 + 16) * HST + mc] = make_ushort4(l1[0], l1[1], l1[2], l1[3]);
        }
        __syncthreads();

        // ---- up: 4 mtiles x 2 ntiles per wave, K=128
        f32x4 accu[4][2];
#pragma unroll
        for (int mt = 0; mt < 4; ++mt) { accu[mt][0] = zz; accu[mt][1] = zz; }
        for (int kbi = 0; kbi < 4; ++kbi) {
            int kb = kbi * 32;
            short8t hh0 = *(const short8t*)&HTh[hbo0 + kb];
            short8t hl0 = *(const short8t*)&HTl[hbo0 + kb];
            short8t hh1 = *(const short8t*)&HTh[hbo1 + kb];
            short8t hl1 = *(const short8t*)&HTl[hbo1 + kb];
#pragma unroll
            for (int mt = 0; mt < 4; ++mt) {
                const ushort* wp = auf + (((l * 16 + (4 * wv + mt)) * 4 + kbi) << 9) + lane8;
                short8t wh = *(const short8t*)wp;
                short8t wl = *(const short8t*)(wp + 65536);
                accu[mt][0] = MFMA16(wh, hh0, accu[mt][0]);
                accu[mt][1] = MFMA16(wh, hh1, accu[mt][1]);
                accu[mt][0] = MFMA16(wh, hl0, accu[mt][0]);
                accu[mt][1] = MFMA16(wh, hl1, accu[mt][1]);
                accu[mt][0] = MFMA16(wl, hh0, accu[mt][0]);
                accu[mt][1] = MFMA16(wl, hh1, accu[mt][1]);
            }
        }
        // ---- up epilogue: residual add
#pragma unroll
        for (int mt = 0; mt < 4; ++mt) {
            int mc = 64 * wv + 16 * mt + 4 * g16;
            float4 ub = *(const float4*)&up_b[l * OD_ + mc];
            float4 gv = *(const float4*)&gu[l * OD_ + mc];
            float4 bv = *(const float4*)&bu[l * OD_ + mc];
            float uba[4] = {ub.x, ub.y, ub.z, ub.w};
            float gva[4] = {gv.x, gv.y, gv.z, gv.w};
            float bva[4] = {bv.x, bv.y, bv.z, bv.w};
            ushort4 xh0 = *(const ushort4*)&XTh[r16 * XST2 + mc];
            ushort4 xl0 = *(const ushort4*)&XTl[r16 * XST2 + mc];
            ushort4 xh1 = *(const ushort4*)&XTh[(r16 + 16) * XST2 + mc];
            ushort4 xl1 = *(const ushort4*)&XTl[(r16 + 16) * XST2 + mc];
            ushort xha0[4] = {xh0.x, xh0.y, xh0.z, xh0.w};
            ushort xla0[4] = {xl0.x, xl0.y, xl0.z, xl0.w};
            ushort xha1[4] = {xh1.x, xh1.y, xh1.z, xh1.w};
            ushort xla1[4] = {xl1.x, xl1.y, xl1.z, xl1.w};
            float nx0[4], nx1[4];
#pragma unroll
            for (int r = 0; r < 4; ++r) {
                float xf0 = __uint_as_float((unsigned)xha0[r] << 16) + __uint_as_float((unsigned)xla0[r] << 16);
                float xf1 = __uint_as_float((unsigned)xha1[r] << 16) + __uint_as_float((unsigned)xla1[r] << 16);
                float v0 = (accu[mt][0][r] + uba[r]) * s_bn * gva[r] + bva[r];
                float v1 = (accu[mt][1][r] + uba[r]) * s_bn * gva[r] + bva[r];
                nx0[r] = fmaxf(v0 + xf0, 0.f);
                nx1[r] = fmaxf(v1 + xf1, 0.f);
            }
            if (l == 0) {
                ushort h0[4], l0[4], h1[4], l1[4];
#pragma unroll
                for (int r = 0; r < 4; ++r) {
                    bf16_split(nx0[r], h0[r], l0[r]);
                    bf16_split(nx1[r], h1[r], l1[r]);
                }
                *(ushort4*)&XTh[r16 * XST2 + mc] = make_ushort4(h0[0], h0[1], h0[2], h0[3]);
                *(ushort4*)&XTl[r16 * XST2 + mc] = make_ushort4(l0[0], l0[1], l0[2], l0[3]);
                *(ushort4*)&XTh[(r16 + 16) * XST2 + mc] = make_ushort4(h1[0], h1[1], h1[2], h1[3]);
                *(ushort4*)&XTl[(r16 + 16) * XST2 + mc] = make_ushort4(l1[0], l1[1], l1[2], l1[3]);
            } else {
                // final: max + mean over 32 pts (16 lanes x 2 ntiles)
#pragma unroll
                for (int r = 0; r < 4; ++r) {
                    float mx = fmaxf(nx0[r], nx1[r]);
                    float sm = nx0[r] + nx1[r];
#pragma unroll
                    for (int off = 1; off < 16; off <<= 1) {
                        mx = fmaxf(mx, __shfl_xor(mx, off));
                        sm += __shfl_xor(sm, off);
                    }
                    if (r16 == 0)
                        out[((size_t)(b * OD_ + mc + r)) * G_ + g] = mx + sm * inv_k;
                }
            }
        }
        __syncthreads();
    }
}

extern "C" void kernel_launch(void* const* d_in, const int* in_sizes, int n_in,
                              void* d_out, int out_size, void* d_ws, size_t ws_size,
                              hipStream_t stream) {
    const float* xyz     = (const float*)d_in[0];
    const float* feat    = (const float*)d_in[1];
    const float* w_embed = (const float*)d_in[2];
    const float* b_embed = (const float*)d_in[3];
    const float* g_embed = (const float*)d_in[4];
    const float* be_embed= (const float*)d_in[5];
    const float* w_lin1  = (const float*)d_in[6];
    const float* g_lin1  = (const float*)d_in[7];
    const float* be_lin1 = (const float*)d_in[8];
    const float* down_w  = (const float*)d_in[9];
    const float* down_b  = (const float*)d_in[10];
    const float* gd      = (const float*)d_in[11];
    const float* bd      = (const float*)d_in[12];
    const float* up_w    = (const float*)d_in[13];
    const float* up_b    = (const float*)d_in[14];
    const float* gu      = (const float*)d_in[15];
    const float* bu      = (const float*)d_in[16];
    float* out = (float*)d_out;

    // workspace carve (~1.38 MB)
    char* w = (char*)d_ws;
    float* wta   = (float*)w;  w += PD_ * OD_ * 4;           // 131072
    float* wEtg  = (float*)w;  w += DIN_ * PD_ * 4;          // 8192
    ushort* alf  = (ushort*)w; w += 2 * 40960 * 2;           // 163840
    ushort* adf  = (ushort*)w; w += 2 * 65536 * 2;           // 262144
    ushort* auf  = (ushort*)w; w += 2 * 65536 * 2;           // 262144
    int* sel     = (int*)w;    w += B_ * G_ * 4;             // 16384
    int* nn      = (int*)w;    w += B_ * G_ * K_ * 4;        // 524288
    double* acc  = (double*)w; w += 16;
    float* stdp  = (float*)w;

    hipMemsetAsync(acc, 0, 2 * sizeof(double), stream);
    prep_kernel<<<256, 256, 0, stream>>>(w_lin1, down_w, up_w, w_embed,
                                         wta, wEtg, alf, adf, auf);
    fps_kernel<<<B_, 512, 0, stream>>>(xyz, sel);
    knn_kernel<<<B_ * G_, 256, 0, stream>>>(xyz, sel, nn);
    std_acc_kernel<<<256, 256, 0, stream>>>(xyz, sel, nn, acc);
    std_fin_kernel<<<1, 1, 0, stream>>>(acc, stdp);
    group_kernel<<<B_ * G_, 256, 0, stream>>>(xyz, feat, wEtg, b_embed, g_embed, be_embed,
        sel, nn, wta, alf, adf, auf, g_lin1, be_lin1, down_b, gd, bd, up_b, gu, bu, stdp, out);
}